// Round 2
// baseline (10.519 us; speedup 1.0000x reference)
//
#include <hip/hip_runtime.h>
#include <utility>
#include <cstddef>

// ---------------------------------------------------------------------------
// Compile-time replication of the Python S2/S3 construction (MAX_L = 3).
// Sparse pattern and coefficients baked in as constexpr; kernel never reads
// the S2/S3 input tensors.
// ---------------------------------------------------------------------------
constexpr int MAXL = 3;
constexpr int NL   = 20;            // len(_l_list(3))
constexpr int NA2  = MAXL;          // 3
constexpr int NA3  = 13;            // S3 keys
constexpr int NOUT = 1 + NA2 + NA3; // 17
constexpr int C    = 16;            // channels

constexpr long long fact_(int n){ long long r=1; for(int i=2;i<=n;i++) r*=i; return r; }
constexpr float multinom_(int x,int y,int z){
    return (float)(fact_(x+y+z)/(fact_(x)*fact_(y)*fact_(z)));
}
constexpr int lidx_(int x,int y,int z){
    int i=0;
    for(int L=0;L<=MAXL;L++)
      for(int lx=L;lx>=0;lx--)
        for(int ly=L-lx;ly>=0;ly--){
          int lz=L-lx-ly;
          if(lx==x&&ly==y&&lz==z) return i;
          i++;
        }
    return -1;
}

struct S3Pat { int n; int l1[400]; int l2[400]; int l3[400]; int a[400]; float v[400]; };
constexpr S3Pat build_s3_(){
    S3Pat p{};
    int a=0;
    for(int m12=0;m12<=MAXL;m12++)
    for(int m13=0;m13<=MAXL-m12;m13++)
    for(int m23=0;m23<=MAXL;m23++){
        if(m12+m23>MAXL||m13+m23>MAXL) continue;
        if(m12+m13<1||m12+m23<1||m13+m23<1) continue;
        for(int ax=0;ax<=m12;ax++)for(int ay=0;ay<=m12-ax;ay++)
        for(int bx=0;bx<=m13;bx++)for(int by=0;by<=m13-bx;by++)
        for(int cx=0;cx<=m23;cx++)for(int cy=0;cy<=m23-cx;cy++){
            int az=m12-ax-ay, bz=m13-bx-by, cz=m23-cx-cy;
            int i1=lidx_(ax+bx,ay+by,az+bz);
            int i2=lidx_(ax+cx,ay+cy,az+cz);
            int i3=lidx_(bx+cx,by+cy,bz+cz);
            float pv=multinom_(ax,ay,az)*multinom_(bx,by,bz)*multinom_(cx,cy,cz);
            bool found=false;
            for(int t=0;t<p.n;t++){
                if(p.l1[t]==i1&&p.l2[t]==i2&&p.l3[t]==i3&&p.a[t]==a){
                    p.v[t]+=pv; found=true; break;
                }
            }
            if(!found){ p.l1[p.n]=i1;p.l2[p.n]=i2;p.l3[p.n]=i3;p.a[p.n]=a;p.v[p.n]=pv;p.n++; }
        }
        a++;
    }
    return p;
}
constexpr S3Pat S3P = build_s3_();

struct S2Pat { int n; int l[NL]; int a[NL]; float v[NL]; };
constexpr S2Pat build_s2_(){
    S2Pat p{};
    int i=0;
    for(int L=0;L<=MAXL;L++)
      for(int lx=L;lx>=0;lx--)
        for(int ly=L-lx;ly>=0;ly--){
            int lz=L-lx-ly;
            if(L>=1){ p.l[p.n]=i; p.a[p.n]=L-1; p.v[p.n]=multinom_(lx,ly,lz); p.n++; }
            i++;
        }
    return p;
}
constexpr S2Pat S2P = build_s2_();

template<size_t... E>
__device__ __forceinline__ void s2_accum_(const float* x, float* o, std::index_sequence<E...>){
    ((o[1 + S2P.a[E]] = fmaf(S2P.v[E] * x[S2P.l[E]], x[S2P.l[E]], o[1 + S2P.a[E]])), ...);
}
template<size_t... E>
__device__ __forceinline__ void s3_accum_(const float* x, float* o, std::index_sequence<E...>){
    ((o[1 + NA2 + S3P.a[E]] =
        fmaf(S3P.v[E] * x[S3P.l1[E]], x[S3P.l2[E]] * x[S3P.l3[E]], o[1 + NA2 + S3P.a[E]])), ...);
}

// ---------------------------------------------------------------------------
// LDS-staged kernel: block = 256 threads = 16 q-rows x 16 channels.
// In-tile  : 16 x 320 floats contiguous -> 1280 float4 coalesced loads.
// Out-tile : 16 x 272 floats contiguous -> 1088 float4 coalesced stores.
// LDS row pads: 328 (mod 32 = 8) and 280 (mod 32 = 24) -> exact 2-way bank
// aliasing for the 64-lane compute-phase accesses (2-way is free, m136).
// ---------------------------------------------------------------------------
constexpr int TQ      = 16;
constexpr int IN_ROW  = NL * C;     // 320
constexpr int IN_PAD  = 328;
constexpr int OUT_ROW = NOUT * C;   // 272
constexpr int OUT_PAD = 280;

__global__ __launch_bounds__(256) void sym_kernel(const float* __restrict__ na,
                                                  float* __restrict__ out){
    __shared__ float sin_[TQ][IN_PAD];
    __shared__ float sout_[TQ][OUT_PAD];
    const int tid = threadIdx.x;
    const size_t q0 = (size_t)blockIdx.x * TQ;

    // ---- stage in: 1280 float4, 5 per thread, fully coalesced ----
    const float4* gin = (const float4*)(na + q0 * IN_ROW);
    #pragma unroll
    for (int j = 0; j < 5; ++j) {
        int i = tid + j * 256;          // float4 index in [0,1280)
        int r = i / 80;                 // 80 float4 per row
        int c = (i - r * 80) * 4;
        float4 v = gin[i];
        *(float4*)&sin_[r][c] = v;
    }
    __syncthreads();

    // ---- compute one fiber per thread from LDS ----
    const int r = tid >> 4;
    const int k = tid & 15;
    float x[NL];
    #pragma unroll
    for (int l = 0; l < NL; ++l) x[l] = sin_[r][k + l * 16];

    float o[NOUT];
    #pragma unroll
    for (int i = 0; i < NOUT; ++i) o[i] = 0.0f;
    o[0] = x[0];
    s2_accum_(x, o, std::make_index_sequence<S2P.n>{});
    s3_accum_(x, o, std::make_index_sequence<S3P.n>{});

    #pragma unroll
    for (int a = 0; a < NOUT; ++a) sout_[r][k + a * 16] = o[a];
    __syncthreads();

    // ---- stage out: 1088 float4, coalesced ----
    float4* gout = (float4*)(out + q0 * OUT_ROW);
    #pragma unroll
    for (int j = 0; j < 5; ++j) {
        int i = tid + j * 256;          // float4 index in [0,1088)
        if (i < 1088) {
            int rr = i / 68;            // 68 float4 per out row
            int cc = (i - rr * 68) * 4;
            gout[i] = *(float4*)&sout_[rr][cc];
        }
    }
}

extern "C" void kernel_launch(void* const* d_in, const int* in_sizes, int n_in,
                              void* d_out, int out_size, void* d_ws, size_t ws_size,
                              hipStream_t stream) {
    const float* na = (const float*)d_in[0];
    float* out = (float*)d_out;
    int nq = in_sizes[0] / (NL * C);        // 8192 q-rows
    int blocks = nq / TQ;                   // 512
    sym_kernel<<<blocks, 256, 0, stream>>>(na, out);
}

// Round 3
// 10.460 us; speedup vs baseline: 1.0056x; 1.0056x over previous
//
#include <hip/hip_runtime.h>
#include <utility>
#include <cstddef>

// ---------------------------------------------------------------------------
// Compile-time replication of the Python S2/S3 construction (MAX_L = 3).
// Sparse pattern and coefficients baked in as constexpr; kernel never reads
// the S2/S3 input tensors.
// ---------------------------------------------------------------------------
constexpr int MAXL = 3;
constexpr int NL   = 20;            // len(_l_list(3))
constexpr int NA2  = MAXL;          // 3
constexpr int NA3  = 13;            // S3 keys
constexpr int NOUT = 1 + NA2 + NA3; // 17
constexpr int C    = 16;            // channels

constexpr long long fact_(int n){ long long r=1; for(int i=2;i<=n;i++) r*=i; return r; }
constexpr float multinom_(int x,int y,int z){
    return (float)(fact_(x+y+z)/(fact_(x)*fact_(y)*fact_(z)));
}
constexpr int lidx_(int x,int y,int z){
    int i=0;
    for(int L=0;L<=MAXL;L++)
      for(int lx=L;lx>=0;lx--)
        for(int ly=L-lx;ly>=0;ly--){
          int lz=L-lx-ly;
          if(lx==x&&ly==y&&lz==z) return i;
          i++;
        }
    return -1;
}

struct S3Pat { int n; int l1[400]; int l2[400]; int l3[400]; int a[400]; float v[400]; };
constexpr S3Pat build_s3_(){
    S3Pat p{};
    int a=0;
    for(int m12=0;m12<=MAXL;m12++)
    for(int m13=0;m13<=MAXL-m12;m13++)
    for(int m23=0;m23<=MAXL;m23++){
        if(m12+m23>MAXL||m13+m23>MAXL) continue;
        if(m12+m13<1||m12+m23<1||m13+m23<1) continue;
        for(int ax=0;ax<=m12;ax++)for(int ay=0;ay<=m12-ax;ay++)
        for(int bx=0;bx<=m13;bx++)for(int by=0;by<=m13-bx;by++)
        for(int cx=0;cx<=m23;cx++)for(int cy=0;cy<=m23-cx;cy++){
            int az=m12-ax-ay, bz=m13-bx-by, cz=m23-cx-cy;
            int i1=lidx_(ax+bx,ay+by,az+bz);
            int i2=lidx_(ax+cx,ay+cy,az+cz);
            int i3=lidx_(bx+cx,by+cy,bz+cz);
            float pv=multinom_(ax,ay,az)*multinom_(bx,by,bz)*multinom_(cx,cy,cz);
            bool found=false;
            for(int t=0;t<p.n;t++){
                if(p.l1[t]==i1&&p.l2[t]==i2&&p.l3[t]==i3&&p.a[t]==a){
                    p.v[t]+=pv; found=true; break;
                }
            }
            if(!found){ p.l1[p.n]=i1;p.l2[p.n]=i2;p.l3[p.n]=i3;p.a[p.n]=a;p.v[p.n]=pv;p.n++; }
        }
        a++;
    }
    return p;
}
constexpr S3Pat S3P = build_s3_();

struct S2Pat { int n; int l[NL]; int a[NL]; float v[NL]; };
constexpr S2Pat build_s2_(){
    S2Pat p{};
    int i=0;
    for(int L=0;L<=MAXL;L++)
      for(int lx=L;lx>=0;lx--)
        for(int ly=L-lx;ly>=0;ly--){
            int lz=L-lx-ly;
            if(L>=1){ p.l[p.n]=i; p.a[p.n]=L-1; p.v[p.n]=multinom_(lx,ly,lz); p.n++; }
            i++;
        }
    return p;
}
constexpr S2Pat S2P = build_s2_();

// Work split across two wave-uniform halves: h0 = out0 + out2 + S3 keys
// [0, SPL.key); h1 = S3 keys [SPL.key, NA3). Terms in S3P are ordered by key,
// so the boundary is a contiguous term range. Balanced by VALU-op estimate.
struct Split { int key; int term; };
constexpr Split find_split_(){
    Split best{0,0}; long bestd = 1L<<40;
    for (int key=0; key<=NA3; ++key){
        int t=0;
        for (int i=0;i<S3P.n;i++) if (S3P.a[i] < key) t++;
        long h0 = 2L*S2P.n + 3L*t;          // out2 + first keys
        long h1 = 3L*(S3P.n - t);
        long d = h0>h1 ? h0-h1 : h1-h0;
        if (d < bestd){ bestd=d; best.key=key; best.term=t; }
    }
    return best;
}
constexpr Split SPL = find_split_();

template<size_t... E>
__device__ __forceinline__ void s2_accum_(const float* x, float* o, std::index_sequence<E...>){
    ((o[1 + S2P.a[E]] = fmaf(S2P.v[E] * x[S2P.l[E]], x[S2P.l[E]], o[1 + S2P.a[E]])), ...);
}
template<size_t OFF, size_t... E>
__device__ __forceinline__ void s3_range_(const float* x, float* o, std::index_sequence<E...>){
    ((o[1 + NA2 + S3P.a[OFF + E]] =
        fmaf(S3P.v[OFF + E] * x[S3P.l1[OFF + E]],
             x[S3P.l2[OFF + E]] * x[S3P.l3[OFF + E]],
             o[1 + NA2 + S3P.a[OFF + E]])), ...);
}

// ---------------------------------------------------------------------------
// Block = 256 threads = 2 halves (wave-uniform) x 8 q-rows x 16 channels.
// tid = h*128 + r*16 + k  -> each wave has a single h value (no divergence).
// Occupancy: 1024 blocks, 4 blocks/CU, 16 waves/CU (4/SIMD) — 2x round 2.
// ---------------------------------------------------------------------------
constexpr int TQ      = 8;
constexpr int IN_ROW  = NL * C;     // 320
constexpr int IN_PAD  = 328;        // mod 32 = 8 -> 2-way bank alias (free)
constexpr int OUT_ROW = NOUT * C;   // 272

__global__ __launch_bounds__(256) void sym_kernel(const float* __restrict__ na,
                                                  float* __restrict__ out){
    __shared__ float sin_[TQ][IN_PAD];
    const int tid = threadIdx.x;
    const size_t q0 = (size_t)blockIdx.x * TQ;

    // ---- stage in: 640 float4, fully coalesced ----
    const float4* gin = (const float4*)(na + q0 * IN_ROW);
    #pragma unroll
    for (int j = 0; j < 3; ++j) {
        int i = tid + j * 256;          // float4 index in [0,640)
        if (i < 640) {
            int r = i / 80;             // 80 float4 per input row
            int c = (i - r * 80) * 4;
            *(float4*)&sin_[r][c] = gin[i];
        }
    }
    __syncthreads();

    // ---- compute: half the polynomial per thread ----
    const int h = tid >> 7;             // wave-uniform half select
    const int r = (tid >> 4) & 7;
    const int k = tid & 15;

    float x[NL];
    #pragma unroll
    for (int l = 0; l < NL; ++l) x[l] = sin_[r][k + l * 16];

    float o[NOUT];
    #pragma unroll
    for (int i = 0; i < NOUT; ++i) o[i] = 0.0f;

    float* ob = out + (q0 + r) * OUT_ROW + k;
    if (h == 0) {
        o[0] = x[0];
        s2_accum_(x, o, std::make_index_sequence<S2P.n>{});
        s3_range_<0>(x, o, std::make_index_sequence<SPL.term>{});
        #pragma unroll
        for (int a = 0; a < 1 + NA2 + SPL.key; ++a) ob[a * C] = o[a];
    } else {
        s3_range_<SPL.term>(x, o, std::make_index_sequence<S3P.n - SPL.term>{});
        #pragma unroll
        for (int a = 1 + NA2 + SPL.key; a < NOUT; ++a) ob[a * C] = o[a];
    }
}

extern "C" void kernel_launch(void* const* d_in, const int* in_sizes, int n_in,
                              void* d_out, int out_size, void* d_ws, size_t ws_size,
                              hipStream_t stream) {
    const float* na = (const float*)d_in[0];
    float* out = (float*)d_out;
    int nq = in_sizes[0] / (NL * C);        // 8192 q-rows
    int blocks = nq / TQ;                   // 1024
    sym_kernel<<<blocks, 256, 0, stream>>>(na, out);
}